// Round 1
// baseline (70.754 us; speedup 1.0000x reference)
//
#include <hip/hip_runtime.h>

#define N 2048
#define B 16
#define STRENGTH 0.1f
#define RADIUS 2310.0f
#define CHUNKS 8          // j-chunks per batch in kernel 1
#define BLK 256

// Kernel 1: per (batch, j-chunk) block. d[b,j] = sum_i |x[b,i]-x[b,j]|,
// w = (d<RADIUS)*STRENGTH; block-reduce partial Sw, Sum(w*x) -> ws.
__global__ __launch_bounds__(BLK) void repulsion_dist_kernel(
    const float* __restrict__ x, float* __restrict__ partials) {
  __shared__ float xs[N];
  const int b = blockIdx.x >> 3;     // / CHUNKS
  const int chunk = blockIdx.x & 7;  // % CHUNKS
  const int tid = threadIdx.x;
  const float* xb = x + b * N;

#pragma unroll
  for (int k = 0; k < N / BLK; ++k) xs[tid + BLK * k] = xb[tid + BLK * k];
  __syncthreads();

  const int j = chunk * BLK + tid;
  const float xj = xs[j];

  // 8 independent accumulators: break the serial FP dependency chain.
  float a0 = 0.f, a1 = 0.f, a2 = 0.f, a3 = 0.f;
  float a4 = 0.f, a5 = 0.f, a6 = 0.f, a7 = 0.f;
  for (int i = 0; i < N; i += 8) {
    a0 += fabsf(xs[i + 0] - xj);
    a1 += fabsf(xs[i + 1] - xj);
    a2 += fabsf(xs[i + 2] - xj);
    a3 += fabsf(xs[i + 3] - xj);
    a4 += fabsf(xs[i + 4] - xj);
    a5 += fabsf(xs[i + 5] - xj);
    a6 += fabsf(xs[i + 6] - xj);
    a7 += fabsf(xs[i + 7] - xj);
  }
  const float d = ((a0 + a1) + (a2 + a3)) + ((a4 + a5) + (a6 + a7));

  float w = (d < RADIUS) ? STRENGTH : 0.f;
  float wx = w * xj;

  // wave (64) reduce, then cross-wave via LDS
#pragma unroll
  for (int m = 32; m >= 1; m >>= 1) {
    w += __shfl_xor(w, m, 64);
    wx += __shfl_xor(wx, m, 64);
  }
  __shared__ float sw_s[4], swx_s[4];
  const int wave = tid >> 6, lane = tid & 63;
  if (lane == 0) { sw_s[wave] = w; swx_s[wave] = wx; }
  __syncthreads();
  if (tid == 0) {
    partials[blockIdx.x * 2 + 0] = (sw_s[0] + sw_s[1]) + (sw_s[2] + sw_s[3]);
    partials[blockIdx.x * 2 + 1] = (swx_s[0] + swx_s[1]) + (swx_s[2] + swx_s[3]);
  }
}

// Kernel 2: single block. 16 lanes per batch: combine partials, compute
// ||Sxw - Sw*x[b,:]||_2, then mean over batches.
__global__ __launch_bounds__(BLK) void repulsion_norm_kernel(
    const float* __restrict__ x, const float* __restrict__ partials,
    float* __restrict__ out) {
  const int tid = threadIdx.x;  // 0..255
  const int b = tid >> 4;       // batch 0..15 (4 batches per wave)
  const int u = tid & 15;       // lane-in-group

  float sw = 0.f, swx = 0.f;
  if (u < CHUNKS) {
    sw  = partials[(b * CHUNKS + u) * 2 + 0];
    swx = partials[(b * CHUNKS + u) * 2 + 1];
  }
#pragma unroll
  for (int m = 8; m >= 1; m >>= 1) {
    sw += __shfl_xor(sw, m, 16);
    swx += __shfl_xor(swx, m, 16);
  }

  const float* xb = x + b * N;
  float acc = 0.f;
#pragma unroll 4
  for (int m = 0; m < N / 16; ++m) {
    const float v = swx - sw * xb[m * 16 + u];
    acc = fmaf(v, v, acc);
  }
#pragma unroll
  for (int m = 8; m >= 1; m >>= 1) acc += __shfl_xor(acc, m, 16);

  __shared__ float norms[B];
  if (u == 0) norms[b] = sqrtf(acc);
  __syncthreads();
  if (tid == 0) {
    float s = 0.f;
#pragma unroll
    for (int i = 0; i < B; ++i) s += norms[i];
    out[0] = s * (1.0f / (float)B);
  }
}

extern "C" void kernel_launch(void* const* d_in, const int* in_sizes, int n_in,
                              void* d_out, int out_size, void* d_ws, size_t ws_size,
                              hipStream_t stream) {
  const float* x = (const float*)d_in[0];
  float* partials = (float*)d_ws;  // B*CHUNKS*2 floats = 1 KiB
  repulsion_dist_kernel<<<B * CHUNKS, BLK, 0, stream>>>(x, partials);
  repulsion_norm_kernel<<<1, BLK, 0, stream>>>(x, partials, (float*)d_out);
}